// Round 7
// baseline (176.051 us; speedup 1.0000x reference)
//
#include <hip/hip_runtime.h>

// B=2, T=2048, C=1024, NH=16, NKV=4, D=64, window read from d_in[9]
// 4-kernel pipeline:
//  1) prep: x -> bf16 + gate | W transposes -> bf16
//  2) gemm_qkv: 64x64 tile, SINGLE-WAVE blocks (no barriers), double-buffered LDS,
//     manual s_waitcnt vmcnt(8) pipeline, fused RoPE+RMS / gate+ve epilogue
//  3) attn: S^T + in-register-P flash attention, XCD-swizzled (R6-verified)
//  4) gemm_proj: same single-wave pipeline, out = Y @ Wproj (fp32)

typedef __bf16 bf16x8 __attribute__((ext_vector_type(8)));
typedef __bf16 bf16x4 __attribute__((ext_vector_type(4)));
typedef float  f32x4  __attribute__((ext_vector_type(4)));

__device__ __forceinline__ void g2l16(const __bf16* gp, __bf16* lp) {
  __builtin_amdgcn_global_load_lds(
      (const __attribute__((address_space(1))) unsigned int*)(const void*)gp,
      (__attribute__((address_space(3))) unsigned int*)(void*)lp, 16, 0, 0);
}

// ---------------- 1) prep ----------------
__global__ void prep(const float* __restrict__ x, __bf16* __restrict__ xb,
                     float* __restrict__ gate, const float* __restrict__ Wg,
                     const float* __restrict__ Wq, const float* __restrict__ Wk,
                     const float* __restrict__ Wv, const float* __restrict__ Wp,
                     __bf16* __restrict__ Wt, __bf16* __restrict__ Wpt) {
  __shared__ float tile[32][33];
  int bid = blockIdx.x;
  if (bid < 2048) {
    int i = (bid * 256 + threadIdx.x) * 8;
    float4 a = *(const float4*)(x + i);
    float4 b = *(const float4*)(x + i + 4);
    bf16x8 o;
    o[0] = (__bf16)a.x; o[1] = (__bf16)a.y; o[2] = (__bf16)a.z; o[3] = (__bf16)a.w;
    o[4] = (__bf16)b.x; o[5] = (__bf16)b.y; o[6] = (__bf16)b.z; o[7] = (__bf16)b.w;
    *(bf16x8*)(xb + i) = o;
    if (threadIdx.x < 8) {
      int row = bid * 2 + (threadIdx.x >> 2);
      int kvh = threadIdx.x & 3;
      float dot = 0.f;
      for (int j = 0; j < 12; ++j) dot += x[(size_t)row * 1024 + j] * Wg[j * 4 + kvh];
      gate[row * 4 + kvh] = 3.f / (1.f + expf(-dot));
    }
    return;
  }
  bid -= 2048;
  int z = bid >> 10, r = bid & 1023;
  int bx = r & 31, by = r >> 5;
  const float* in; __bf16* out; int Cc;
  if (z == 0)      { in = Wq; out = Wt;               Cc = 1024; }
  else if (z == 1) { in = Wk; out = Wt + 1024 * 1024; Cc = 256; }
  else if (z == 2) { in = Wv; out = Wt + 1280 * 1024; Cc = 256; }
  else             { in = Wp; out = Wpt;              Cc = 1024; }
  int c0 = bx * 32, r0 = by * 32;
  if (c0 >= Cc) return;
  int tx = threadIdx.x & 31, ty = threadIdx.x >> 5;
  for (int i = ty; i < 32; i += 8) tile[i][tx] = in[(size_t)(r0 + i) * Cc + c0 + tx];
  __syncthreads();
  for (int i = ty; i < 32; i += 8) out[(size_t)(c0 + i) * 1024 + r0 + tx] = (__bf16)tile[tx][i];
}

// ---------------- 2) QKV GEMM: 64x64, single wave, vmcnt-pipelined ----------------
// grid (24, 64). n0 spans exactly one head (64 cols).
__global__ __launch_bounds__(64, 2) void gemm_qkv(const __bf16* __restrict__ A,
                                                  const __bf16* __restrict__ Bt,
                                                  const float* __restrict__ cosp,
                                                  const float* __restrict__ sinp,
                                                  const float* __restrict__ gate,
                                                  const float* __restrict__ ve,
                                                  __bf16* __restrict__ Qb,
                                                  __bf16* __restrict__ Kb,
                                                  __bf16* __restrict__ Vt) {
  const int K = 1024;
  __shared__ __bf16 As[2][64 * 32];
  __shared__ __bf16 Bs[2][64 * 32];
  int lane = threadIdx.x, quad = lane >> 4, l16 = lane & 15;
  int m0 = blockIdx.y * 64, n0 = blockIdx.x * 64;

  f32x4 zero = {0.f, 0.f, 0.f, 0.f};
  f32x4 acc[4][4];
  for (int i = 0; i < 4; ++i) for (int j = 0; j < 4; ++j) acc[i][j] = zero;

  int rsub = lane >> 2, cc = (lane & 3) * 8;
  const __bf16* gA = A  + (size_t)(m0 + rsub) * K + cc;
  const __bf16* gB = Bt + (size_t)(n0 + rsub) * K + cc;

  // prologue: tile 0 -> buf 0
  for (int c = 0; c < 4; ++c) {
    g2l16(gA + c * 16 * K, &As[0][c * 512]);
    g2l16(gB + c * 16 * K, &Bs[0][c * 512]);
  }
  for (int it = 0; it < 32; ++it) {
    int cur = it & 1;
    if (it + 1 < 32) {
      int k1 = (it + 1) * 32;
      for (int c = 0; c < 4; ++c) {
        g2l16(gA + c * 16 * K + k1, &As[cur ^ 1][c * 512]);
        g2l16(gB + c * 16 * K + k1, &Bs[cur ^ 1][c * 512]);
      }
      __builtin_amdgcn_sched_barrier(0);
      __builtin_amdgcn_s_waitcnt(0xF78);  // vmcnt(8): tile `cur` complete, next 8 in flight
    } else {
      __builtin_amdgcn_sched_barrier(0);
      __builtin_amdgcn_s_waitcnt(0xF70);  // vmcnt(0)
    }
    __builtin_amdgcn_sched_barrier(0);
    bf16x8 af[4], bfr[4];
    for (int i = 0; i < 4; ++i) {
      af[i]  = *(const bf16x8*)(&As[cur][(i * 16 + l16) * 32 + quad * 8]);
      bfr[i] = *(const bf16x8*)(&Bs[cur][(i * 16 + l16) * 32 + quad * 8]);
    }
    for (int i = 0; i < 4; ++i)
      for (int j = 0; j < 4; ++j)
        acc[i][j] = __builtin_amdgcn_mfma_f32_16x16x32_bf16(af[i], bfr[j], acc[i][j], 0, 0, 0);
  }

  int ncol = n0;  // head-aligned 64-wide strip
  if (ncol < 1280) {
    __bf16* dstbase;
    if (ncol < 1024) dstbase = Qb + (size_t)(ncol >> 6) * 2048 * 64;
    else             dstbase = Kb + (size_t)((ncol - 1024) >> 6) * 2048 * 64;
    int nheads = (ncol < 1024) ? 16 : 4;
    for (int i = 0; i < 4; ++i) {
      for (int r = 0; r < 4; ++r) {
        int m = m0 + i * 16 + quad * 4 + r;
        int bb = m >> 11, t = m & 2047;
        float c0 = cosp[t * 32 + l16], c1 = cosp[t * 32 + 16 + l16];
        float s0 = sinp[t * 32 + l16], s1 = sinp[t * 32 + 16 + l16];
        float v0 = acc[i][0][r], v1 = acc[i][1][r], v2 = acc[i][2][r], v3 = acc[i][3][r];
        float r0 = v0 * c0 + v2 * s0;
        float r1 = v1 * c1 + v3 * s1;
        float r2 = v2 * c0 - v0 * s0;
        float r3 = v3 * c1 - v1 * s1;
        float ss = r0 * r0 + r1 * r1 + r2 * r2 + r3 * r3;
        ss += __shfl_xor(ss, 1, 64); ss += __shfl_xor(ss, 2, 64);
        ss += __shfl_xor(ss, 4, 64); ss += __shfl_xor(ss, 8, 64);
        float sc = rsqrtf(ss * (1.f / 64.f) + 1e-6f) * 1.2f;
        __bf16* dst = dstbase + ((size_t)bb * nheads * 2048 + t) * 64;
        dst[l16]      = (__bf16)(r0 * sc);
        dst[16 + l16] = (__bf16)(r1 * sc);
        dst[32 + l16] = (__bf16)(r2 * sc);
        dst[48 + l16] = (__bf16)(r3 * sc);
      }
    }
  } else {
    int kvh = (ncol - 1280) >> 6;
    for (int i = 0; i < 4; ++i) {
      int mbase = m0 + i * 16 + quad * 4;
      int bb = mbase >> 11;
      int t0 = mbase & 2047;
      float g4[4];
      for (int r = 0; r < 4; ++r) g4[r] = gate[(mbase + r) * 4 + kvh];
      for (int j = 0; j < 4; ++j) {
        int d = j * 16 + l16;
        bf16x4 pk;
        for (int r = 0; r < 4; ++r)
          pk[r] = (__bf16)(acc[i][j][r] + g4[r] * ve[(size_t)(mbase + r) * 256 + kvh * 64 + d]);
        *(bf16x4*)(Vt + ((size_t)(bb * 4 + kvh) * 64 + d) * 2048 + t0) = pk;
      }
    }
  }
}

// ---------------- 3) flash attention: S^T + in-register P, XCD-swizzled ----------------
__global__ __launch_bounds__(512) void attn_kernel(
    const __bf16* __restrict__ Q, const __bf16* __restrict__ K,
    const __bf16* __restrict__ Vt, __bf16* __restrict__ Y,
    const int* __restrict__ winp) {
  const int T = 2048, D = 64, NH = 16, NKV = 4;
  int fid = blockIdx.x + 16 * blockIdx.y + 256 * blockIdx.z;
  int g8 = fid & 7, j = fid >> 3;
  int b = g8 >> 2, kvh = g8 & 3;
  int h = kvh * 4 + (j & 3);
  int qb = (15 - (j >> 2)) * 128;  // LPT
  int tid = threadIdx.x, w = tid >> 6, lane = tid & 63, quad = lane >> 4, l16 = lane & 15;
  int window = *winp;
  int qw = qb + w * 16;

  __shared__ __bf16 Ks[64 * 72];
  __shared__ __bf16 Vs[64 * 72];

  const __bf16* Qbase = Q + ((size_t)(b * NH + h)) * T * D;
  bf16x8 qf0 = *(const bf16x8*)(Qbase + (size_t)(qw + l16) * D + quad * 8);
  bf16x8 qf1 = *(const bf16x8*)(Qbase + (size_t)(qw + l16) * D + quad * 8 + 32);

  const __bf16* Kbase = K  + ((size_t)(b * NKV + kvh)) * T * D;
  const __bf16* Vbase = Vt + ((size_t)(b * NKV + kvh)) * D * T;

  float lsum = 0.f;
  f32x4 zero = {0.f, 0.f, 0.f, 0.f};
  f32x4 o[4] = {zero, zero, zero, zero};

  int kw = qb - window;
  int kstart = (kw > 0) ? (kw & ~63) : 0;
  int kend = qb + 128;
  const float c1 = 0.125f * 1.44269504f;
  const float c2 = 12.0f * 1.44269504f;
  int q = qw + l16;

  int sr = tid >> 3, sc8 = (tid & 7) * 8;
  bf16x8 kr = *(const bf16x8*)(Kbase + (size_t)(kstart + sr) * D + sc8);
  bf16x8 vr = *(const bf16x8*)(Vbase + (size_t)sr * T + kstart + sc8);

  for (int kt = kstart; kt < kend; kt += 64) {
    __syncthreads();
    *(bf16x8*)(&Ks[sr * 72 + sc8]) = kr;
    *(bf16x8*)(&Vs[sr * 72 + sc8]) = vr;
    __syncthreads();
    int ktn = kt + 64;
    if (ktn < kend) {
      kr = *(const bf16x8*)(Kbase + (size_t)(ktn + sr) * D + sc8);
      vr = *(const bf16x8*)(Vbase + (size_t)sr * T + ktn + sc8);
    }
    if (kt > qw + 15 || kt + 63 < qw - window) continue;
    bool clean = (kt + 63 <= qw) && (qw + 15 - kt <= window);

    for (int g = 0; g < 2; ++g) {
      int kb = g * 32;
      bf16x8 ka0 = *(const bf16x8*)(&Ks[(kb + l16) * 72 + quad * 8]);
      bf16x8 ka1 = *(const bf16x8*)(&Ks[(kb + l16) * 72 + quad * 8 + 32]);
      f32x4 sA = __builtin_amdgcn_mfma_f32_16x16x32_bf16(ka0, qf0, zero, 0, 0, 0);
      sA       = __builtin_amdgcn_mfma_f32_16x16x32_bf16(ka1, qf1, sA, 0, 0, 0);
      bf16x8 kb0 = *(const bf16x8*)(&Ks[(kb + 16 + l16) * 72 + quad * 8]);
      bf16x8 kb1 = *(const bf16x8*)(&Ks[(kb + 16 + l16) * 72 + quad * 8 + 32]);
      f32x4 sB = __builtin_amdgcn_mfma_f32_16x16x32_bf16(kb0, qf0, zero, 0, 0, 0);
      sB       = __builtin_amdgcn_mfma_f32_16x16x32_bf16(kb1, qf1, sB, 0, 0, 0);

      bf16x8 pf;
      if (clean) {
        for (int r = 0; r < 4; ++r) {
          float pA = __builtin_amdgcn_exp2f(sA[r] * c1 - c2);
          float pB = __builtin_amdgcn_exp2f(sB[r] * c1 - c2);
          lsum += pA + pB;
          pf[r] = (__bf16)pA; pf[4 + r] = (__bf16)pB;
        }
      } else {
        for (int r = 0; r < 4; ++r) {
          int kiA = kt + kb + quad * 4 + r;
          int kiB = kiA + 16;
          bool okA = (kiA <= q) && (q - kiA <= window);
          bool okB = (kiB <= q) && (q - kiB <= window);
          float pA = okA ? __builtin_amdgcn_exp2f(sA[r] * c1 - c2) : 0.f;
          float pB = okB ? __builtin_amdgcn_exp2f(sB[r] * c1 - c2) : 0.f;
          lsum += pA + pB;
          pf[r] = (__bf16)pA; pf[4 + r] = (__bf16)pB;
        }
      }
      for (int dc = 0; dc < 4; ++dc) {
        bf16x4 va = *(const bf16x4*)(&Vs[(dc * 16 + l16) * 72 + kb + quad * 4]);
        bf16x4 vb = *(const bf16x4*)(&Vs[(dc * 16 + l16) * 72 + kb + 16 + quad * 4]);
        bf16x8 vf;
        vf[0] = va[0]; vf[1] = va[1]; vf[2] = va[2]; vf[3] = va[3];
        vf[4] = vb[0]; vf[5] = vb[1]; vf[6] = vb[2]; vf[7] = vb[3];
        o[dc] = __builtin_amdgcn_mfma_f32_16x16x32_bf16(vf, pf, o[dc], 0, 0, 0);
      }
    }
  }

  float l = lsum;
  l += __shfl_xor(l, 16, 64);
  l += __shfl_xor(l, 32, 64);
  float inv = 1.f / l;
  size_t base = ((size_t)(b * T + q)) * 1024 + h * 64 + quad * 4;
  for (int dc = 0; dc < 4; ++dc) {
    bf16x4 pk;
    pk[0] = (__bf16)(o[dc][0] * inv); pk[1] = (__bf16)(o[dc][1] * inv);
    pk[2] = (__bf16)(o[dc][2] * inv); pk[3] = (__bf16)(o[dc][3] * inv);
    *(bf16x4*)(Y + base + dc * 16) = pk;
  }
}

// ---------------- 4) proj GEMM: 64x64, single wave, vmcnt-pipelined ----------------
__global__ __launch_bounds__(64, 2) void gemm_proj(const __bf16* __restrict__ A,
                                                   const __bf16* __restrict__ Bt,
                                                   float* __restrict__ C,
                                                   int M, int N, int K) {
  __shared__ __bf16 As[2][64 * 32];
  __shared__ __bf16 Bs[2][64 * 32];
  int lane = threadIdx.x, quad = lane >> 4, l16 = lane & 15;
  int m0 = blockIdx.y * 64, n0 = blockIdx.x * 64;

  f32x4 zero = {0.f, 0.f, 0.f, 0.f};
  f32x4 acc[4][4];
  for (int i = 0; i < 4; ++i) for (int j = 0; j < 4; ++j) acc[i][j] = zero;

  int rsub = lane >> 2, cc = (lane & 3) * 8;
  const __bf16* gA = A  + (size_t)(m0 + rsub) * K + cc;
  const __bf16* gB = Bt + (size_t)(n0 + rsub) * K + cc;

  for (int c = 0; c < 4; ++c) {
    g2l16(gA + c * 16 * K, &As[0][c * 512]);
    g2l16(gB + c * 16 * K, &Bs[0][c * 512]);
  }
  int iters = K / 32;
  for (int it = 0; it < iters; ++it) {
    int cur = it & 1;
    if (it + 1 < iters) {
      int k1 = (it + 1) * 32;
      for (int c = 0; c < 4; ++c) {
        g2l16(gA + c * 16 * K + k1, &As[cur ^ 1][c * 512]);
        g2l16(gB + c * 16 * K + k1, &Bs[cur ^ 1][c * 512]);
      }
      __builtin_amdgcn_sched_barrier(0);
      __builtin_amdgcn_s_waitcnt(0xF78);
    } else {
      __builtin_amdgcn_sched_barrier(0);
      __builtin_amdgcn_s_waitcnt(0xF70);
    }
    __builtin_amdgcn_sched_barrier(0);
    bf16x8 af[4], bfr[4];
    for (int i = 0; i < 4; ++i) {
      af[i]  = *(const bf16x8*)(&As[cur][(i * 16 + l16) * 32 + quad * 8]);
      bfr[i] = *(const bf16x8*)(&Bs[cur][(i * 16 + l16) * 32 + quad * 8]);
    }
    for (int i = 0; i < 4; ++i)
      for (int j = 0; j < 4; ++j)
        acc[i][j] = __builtin_amdgcn_mfma_f32_16x16x32_bf16(af[i], bfr[j], acc[i][j], 0, 0, 0);
  }
  for (int i = 0; i < 4; ++i)
    for (int j = 0; j < 4; ++j)
      for (int r = 0; r < 4; ++r)
        C[(size_t)(m0 + i * 16 + quad * 4 + r) * N + n0 + j * 16 + l16] = acc[i][j][r];
}

// ---------------- launch ----------------
extern "C" void kernel_launch(void* const* d_in, const int* in_sizes, int n_in,
                              void* d_out, int out_size, void* d_ws, size_t ws_size,
                              hipStream_t stream) {
  const float* x     = (const float*)d_in[0];
  const float* ve    = (const float*)d_in[1];
  const float* cosp  = (const float*)d_in[2];
  const float* sinp  = (const float*)d_in[3];
  const float* Wq    = (const float*)d_in[4];
  const float* Wk    = (const float*)d_in[5];
  const float* Wv    = (const float*)d_in[6];
  const float* Wproj = (const float*)d_in[7];
  const float* Wg    = (const float*)d_in[8];
  const int*   win   = (const int*)d_in[9];
  float* out = (float*)d_out;

  char* ws = (char*)d_ws;
  __bf16* xb   = (__bf16*)(ws);                //  8,388,608  [4096][1024]
  __bf16* Wt   = (__bf16*)(ws + 8388608);      //  3,145,728  [1536][1024]
  __bf16* Wpt  = (__bf16*)(ws + 11534336);     //  2,097,152  [1024][1024]
  float*  gate = (float*)(ws + 13631488);      //     65,536  [4096][4]
  __bf16* Qb   = (__bf16*)(ws + 13697024);     //  8,388,608  [2][16][2048][64]
  __bf16* Kb   = (__bf16*)(ws + 22085632);     //  2,097,152  [2][4][2048][64]
  __bf16* Vt   = (__bf16*)(ws + 24182784);     //  2,097,152  [2][4][64][2048]
  __bf16* Y    = (__bf16*)(ws + 26279936);     //  8,388,608  [4096][1024] -> ends 34,668,544

  prep<<<2048 + 4096, 256, 0, stream>>>(x, xb, gate, Wg, Wq, Wk, Wv, Wproj, Wt, Wpt);
  gemm_qkv<<<dim3(24, 64), 64, 0, stream>>>(xb, Wt, cosp, sinp, gate, ve, Qb, Kb, Vt);
  attn_kernel<<<dim3(16, 16, 2), 512, 0, stream>>>(Qb, Kb, Vt, Y, win);
  gemm_proj<<<dim3(16, 64), 64, 0, stream>>>(Y, Wpt, out, 4096, 1024, 1024);
}

// Round 8
// 163.485 us; speedup vs baseline: 1.0769x; 1.0769x over previous
//
#include <hip/hip_runtime.h>

// B=2, T=2048, C=1024, NH=16, NKV=4, D=64, window read from d_in[9]
// 4-kernel pipeline (R6 structure + XCD-locality grid order for GEMMs):
//  1) prep: x -> bf16 + gate | W transposes -> bf16
//  2) gemm_qkv: 64x128 tile, BK=64, global_load_lds, grid(m=64, n=12) so XCD = m&7:
//     per-XCD A-tiles stay L2-resident across n-phases; fused RoPE+RMS / gate+ve
//  3) attn: S^T + in-register-P flash attention, XCD-swizzled (R6-verified)
//  4) gemm_proj: same, grid(m=64, n=8): out = Y @ Wproj (fp32)

typedef __bf16 bf16x8 __attribute__((ext_vector_type(8)));
typedef __bf16 bf16x4 __attribute__((ext_vector_type(4)));
typedef float  f32x4  __attribute__((ext_vector_type(4)));

__device__ __forceinline__ void g2l16(const __bf16* gp, __bf16* lp) {
  __builtin_amdgcn_global_load_lds(
      (const __attribute__((address_space(1))) unsigned int*)(const void*)gp,
      (__attribute__((address_space(3))) unsigned int*)(void*)lp, 16, 0, 0);
}

// ---------------- 1) prep ----------------
__global__ void prep(const float* __restrict__ x, __bf16* __restrict__ xb,
                     float* __restrict__ gate, const float* __restrict__ Wg,
                     const float* __restrict__ Wq, const float* __restrict__ Wk,
                     const float* __restrict__ Wv, const float* __restrict__ Wp,
                     __bf16* __restrict__ Wt, __bf16* __restrict__ Wpt) {
  __shared__ float tile[32][33];
  int bid = blockIdx.x;
  if (bid < 2048) {
    int i = (bid * 256 + threadIdx.x) * 8;
    float4 a = *(const float4*)(x + i);
    float4 b = *(const float4*)(x + i + 4);
    bf16x8 o;
    o[0] = (__bf16)a.x; o[1] = (__bf16)a.y; o[2] = (__bf16)a.z; o[3] = (__bf16)a.w;
    o[4] = (__bf16)b.x; o[5] = (__bf16)b.y; o[6] = (__bf16)b.z; o[7] = (__bf16)b.w;
    *(bf16x8*)(xb + i) = o;
    if (threadIdx.x < 8) {
      int row = bid * 2 + (threadIdx.x >> 2);
      int kvh = threadIdx.x & 3;
      float dot = 0.f;
      for (int j = 0; j < 12; ++j) dot += x[(size_t)row * 1024 + j] * Wg[j * 4 + kvh];
      gate[row * 4 + kvh] = 3.f / (1.f + expf(-dot));
    }
    return;
  }
  bid -= 2048;
  int z = bid >> 10, r = bid & 1023;
  int bx = r & 31, by = r >> 5;
  const float* in; __bf16* out; int Cc;
  if (z == 0)      { in = Wq; out = Wt;               Cc = 1024; }
  else if (z == 1) { in = Wk; out = Wt + 1024 * 1024; Cc = 256; }
  else if (z == 2) { in = Wv; out = Wt + 1280 * 1024; Cc = 256; }
  else             { in = Wp; out = Wpt;              Cc = 1024; }
  int c0 = bx * 32, r0 = by * 32;
  if (c0 >= Cc) return;
  int tx = threadIdx.x & 31, ty = threadIdx.x >> 5;
  for (int i = ty; i < 32; i += 8) tile[i][tx] = in[(size_t)(r0 + i) * Cc + c0 + tx];
  __syncthreads();
  for (int i = ty; i < 32; i += 8) out[(size_t)(c0 + i) * 1024 + r0 + tx] = (__bf16)tile[tx][i];
}

// ---------------- 2) QKV GEMM 64x128, BK=64, fused head epilogue ----------------
// grid (64, 12): m on x so flat id = m + 64*n -> XCD = m&7 (A-tiles L2-resident per XCD).
__global__ __launch_bounds__(256) void gemm_qkv(const __bf16* __restrict__ A,
                                                const __bf16* __restrict__ Bt,
                                                const float* __restrict__ cosp,
                                                const float* __restrict__ sinp,
                                                const float* __restrict__ gate,
                                                const float* __restrict__ ve,
                                                __bf16* __restrict__ Qb,
                                                __bf16* __restrict__ Kb,
                                                __bf16* __restrict__ Vt) {
  const int K = 1024;
  __shared__ __bf16 As[2 * 64 * 32];   // [half][row][32]
  __shared__ __bf16 Bs[2 * 128 * 32];
  int tid = threadIdx.x;
  int m0 = blockIdx.x * 64, n0 = blockIdx.y * 128;
  int w = tid >> 6, lane = tid & 63, quad = lane >> 4, l16 = lane & 15;
  int wm = (w >> 1) * 32, wn = (w & 1) * 64;

  f32x4 zero = {0.f, 0.f, 0.f, 0.f};
  f32x4 acc[2][4];
  for (int i = 0; i < 2; ++i) for (int j = 0; j < 4; ++j) acc[i][j] = zero;

  int rsub = lane >> 2, cc = (lane & 3) * 8;
  const __bf16* gA  = A  + (size_t)(m0 + w * 16 + rsub) * K + cc;
  const __bf16* gB0 = Bt + (size_t)(n0 + (2 * w) * 16 + rsub) * K + cc;
  const __bf16* gB1 = Bt + (size_t)(n0 + (2 * w + 1) * 16 + rsub) * K + cc;
  __bf16* lA0  = &As[w * 512];            __bf16* lA1  = &As[2048 + w * 512];
  __bf16* lB00 = &Bs[(2 * w) * 512];      __bf16* lB01 = &Bs[4096 + (2 * w) * 512];
  __bf16* lB10 = &Bs[(2 * w + 1) * 512];  __bf16* lB11 = &Bs[4096 + (2 * w + 1) * 512];

  for (int k0 = 0; k0 < K; k0 += 64) {
    __syncthreads();
    g2l16(gA + k0, lA0);       g2l16(gA + k0 + 32, lA1);
    g2l16(gB0 + k0, lB00);     g2l16(gB0 + k0 + 32, lB01);
    g2l16(gB1 + k0, lB10);     g2l16(gB1 + k0 + 32, lB11);
    __syncthreads();
    for (int ks = 0; ks < 2; ++ks) {
      bf16x8 af[2], bfr[4];
      for (int i = 0; i < 2; ++i)
        af[i] = *(const bf16x8*)(&As[ks * 2048 + (wm + i * 16 + l16) * 32 + quad * 8]);
      for (int j = 0; j < 4; ++j)
        bfr[j] = *(const bf16x8*)(&Bs[ks * 4096 + (wn + j * 16 + l16) * 32 + quad * 8]);
      for (int i = 0; i < 2; ++i)
        for (int j = 0; j < 4; ++j)
          acc[i][j] = __builtin_amdgcn_mfma_f32_16x16x32_bf16(af[i], bfr[j], acc[i][j], 0, 0, 0);
    }
  }

  int ncol = n0 + wn;  // head-aligned 64-wide strip
  if (ncol < 1280) {
    __bf16* dstbase;
    if (ncol < 1024) dstbase = Qb + (size_t)(ncol >> 6) * 2048 * 64;
    else             dstbase = Kb + (size_t)((ncol - 1024) >> 6) * 2048 * 64;
    int nheads = (ncol < 1024) ? 16 : 4;
    for (int i = 0; i < 2; ++i) {
      for (int r = 0; r < 4; ++r) {
        int m = m0 + wm + i * 16 + quad * 4 + r;
        int bb = m >> 11, t = m & 2047;
        float c0 = cosp[t * 32 + l16], c1 = cosp[t * 32 + 16 + l16];
        float s0 = sinp[t * 32 + l16], s1 = sinp[t * 32 + 16 + l16];
        float v0 = acc[i][0][r], v1 = acc[i][1][r], v2 = acc[i][2][r], v3 = acc[i][3][r];
        float r0 = v0 * c0 + v2 * s0;
        float r1 = v1 * c1 + v3 * s1;
        float r2 = v2 * c0 - v0 * s0;
        float r3 = v3 * c1 - v1 * s1;
        float ss = r0 * r0 + r1 * r1 + r2 * r2 + r3 * r3;
        ss += __shfl_xor(ss, 1, 64); ss += __shfl_xor(ss, 2, 64);
        ss += __shfl_xor(ss, 4, 64); ss += __shfl_xor(ss, 8, 64);
        float sc = rsqrtf(ss * (1.f / 64.f) + 1e-6f) * 1.2f;
        __bf16* dst = dstbase + ((size_t)bb * nheads * 2048 + t) * 64;
        dst[l16]      = (__bf16)(r0 * sc);
        dst[16 + l16] = (__bf16)(r1 * sc);
        dst[32 + l16] = (__bf16)(r2 * sc);
        dst[48 + l16] = (__bf16)(r3 * sc);
      }
    }
  } else {
    int kvh = (ncol - 1280) >> 6;
    for (int i = 0; i < 2; ++i) {
      int mbase = m0 + wm + i * 16 + quad * 4;
      int bb = mbase >> 11;
      int t0 = mbase & 2047;
      float g4[4];
      for (int r = 0; r < 4; ++r) g4[r] = gate[(mbase + r) * 4 + kvh];
      for (int j = 0; j < 4; ++j) {
        int d = j * 16 + l16;
        bf16x4 pk;
        for (int r = 0; r < 4; ++r)
          pk[r] = (__bf16)(acc[i][j][r] + g4[r] * ve[(size_t)(mbase + r) * 256 + kvh * 64 + d]);
        *(bf16x4*)(Vt + ((size_t)(bb * 4 + kvh) * 64 + d) * 2048 + t0) = pk;
      }
    }
  }
}

// ---------------- 3) flash attention: S^T + in-register P, XCD-swizzled ----------------
__global__ __launch_bounds__(512) void attn_kernel(
    const __bf16* __restrict__ Q, const __bf16* __restrict__ K,
    const __bf16* __restrict__ Vt, __bf16* __restrict__ Y,
    const int* __restrict__ winp) {
  const int T = 2048, D = 64, NH = 16, NKV = 4;
  int fid = blockIdx.x + 16 * blockIdx.y + 256 * blockIdx.z;
  int g8 = fid & 7, j = fid >> 3;
  int b = g8 >> 2, kvh = g8 & 3;
  int h = kvh * 4 + (j & 3);
  int qb = (15 - (j >> 2)) * 128;  // LPT
  int tid = threadIdx.x, w = tid >> 6, lane = tid & 63, quad = lane >> 4, l16 = lane & 15;
  int window = *winp;
  int qw = qb + w * 16;

  __shared__ __bf16 Ks[64 * 72];
  __shared__ __bf16 Vs[64 * 72];

  const __bf16* Qbase = Q + ((size_t)(b * NH + h)) * T * D;
  bf16x8 qf0 = *(const bf16x8*)(Qbase + (size_t)(qw + l16) * D + quad * 8);
  bf16x8 qf1 = *(const bf16x8*)(Qbase + (size_t)(qw + l16) * D + quad * 8 + 32);

  const __bf16* Kbase = K  + ((size_t)(b * NKV + kvh)) * T * D;
  const __bf16* Vbase = Vt + ((size_t)(b * NKV + kvh)) * D * T;

  float lsum = 0.f;
  f32x4 zero = {0.f, 0.f, 0.f, 0.f};
  f32x4 o[4] = {zero, zero, zero, zero};

  int kw = qb - window;
  int kstart = (kw > 0) ? (kw & ~63) : 0;
  int kend = qb + 128;
  const float c1 = 0.125f * 1.44269504f;
  const float c2 = 12.0f * 1.44269504f;
  int q = qw + l16;

  int sr = tid >> 3, sc8 = (tid & 7) * 8;
  bf16x8 kr = *(const bf16x8*)(Kbase + (size_t)(kstart + sr) * D + sc8);
  bf16x8 vr = *(const bf16x8*)(Vbase + (size_t)sr * T + kstart + sc8);

  for (int kt = kstart; kt < kend; kt += 64) {
    __syncthreads();
    *(bf16x8*)(&Ks[sr * 72 + sc8]) = kr;
    *(bf16x8*)(&Vs[sr * 72 + sc8]) = vr;
    __syncthreads();
    int ktn = kt + 64;
    if (ktn < kend) {
      kr = *(const bf16x8*)(Kbase + (size_t)(ktn + sr) * D + sc8);
      vr = *(const bf16x8*)(Vbase + (size_t)sr * T + ktn + sc8);
    }
    if (kt > qw + 15 || kt + 63 < qw - window) continue;
    bool clean = (kt + 63 <= qw) && (qw + 15 - kt <= window);

    for (int g = 0; g < 2; ++g) {
      int kb = g * 32;
      bf16x8 ka0 = *(const bf16x8*)(&Ks[(kb + l16) * 72 + quad * 8]);
      bf16x8 ka1 = *(const bf16x8*)(&Ks[(kb + l16) * 72 + quad * 8 + 32]);
      f32x4 sA = __builtin_amdgcn_mfma_f32_16x16x32_bf16(ka0, qf0, zero, 0, 0, 0);
      sA       = __builtin_amdgcn_mfma_f32_16x16x32_bf16(ka1, qf1, sA, 0, 0, 0);
      bf16x8 kb0 = *(const bf16x8*)(&Ks[(kb + 16 + l16) * 72 + quad * 8]);
      bf16x8 kb1 = *(const bf16x8*)(&Ks[(kb + 16 + l16) * 72 + quad * 8 + 32]);
      f32x4 sB = __builtin_amdgcn_mfma_f32_16x16x32_bf16(kb0, qf0, zero, 0, 0, 0);
      sB       = __builtin_amdgcn_mfma_f32_16x16x32_bf16(kb1, qf1, sB, 0, 0, 0);

      bf16x8 pf;
      if (clean) {
        for (int r = 0; r < 4; ++r) {
          float pA = __builtin_amdgcn_exp2f(sA[r] * c1 - c2);
          float pB = __builtin_amdgcn_exp2f(sB[r] * c1 - c2);
          lsum += pA + pB;
          pf[r] = (__bf16)pA; pf[4 + r] = (__bf16)pB;
        }
      } else {
        for (int r = 0; r < 4; ++r) {
          int kiA = kt + kb + quad * 4 + r;
          int kiB = kiA + 16;
          bool okA = (kiA <= q) && (q - kiA <= window);
          bool okB = (kiB <= q) && (q - kiB <= window);
          float pA = okA ? __builtin_amdgcn_exp2f(sA[r] * c1 - c2) : 0.f;
          float pB = okB ? __builtin_amdgcn_exp2f(sB[r] * c1 - c2) : 0.f;
          lsum += pA + pB;
          pf[r] = (__bf16)pA; pf[4 + r] = (__bf16)pB;
        }
      }
      for (int dc = 0; dc < 4; ++dc) {
        bf16x4 va = *(const bf16x4*)(&Vs[(dc * 16 + l16) * 72 + kb + quad * 4]);
        bf16x4 vb = *(const bf16x4*)(&Vs[(dc * 16 + l16) * 72 + kb + 16 + quad * 4]);
        bf16x8 vf;
        vf[0] = va[0]; vf[1] = va[1]; vf[2] = va[2]; vf[3] = va[3];
        vf[4] = vb[0]; vf[5] = vb[1]; vf[6] = vb[2]; vf[7] = vb[3];
        o[dc] = __builtin_amdgcn_mfma_f32_16x16x32_bf16(vf, pf, o[dc], 0, 0, 0);
      }
    }
  }

  float l = lsum;
  l += __shfl_xor(l, 16, 64);
  l += __shfl_xor(l, 32, 64);
  float inv = 1.f / l;
  size_t base = ((size_t)(b * T + q)) * 1024 + h * 64 + quad * 4;
  for (int dc = 0; dc < 4; ++dc) {
    bf16x4 pk;
    pk[0] = (__bf16)(o[dc][0] * inv); pk[1] = (__bf16)(o[dc][1] * inv);
    pk[2] = (__bf16)(o[dc][2] * inv); pk[3] = (__bf16)(o[dc][3] * inv);
    *(bf16x4*)(Y + base + dc * 16) = pk;
  }
}

// ---------------- 4) proj GEMM 64x128, BK=64 (fp32 out) ----------------
// grid (64, 8): m on x -> XCD = m&7; per-XCD A(Y)-tiles L2-resident across n-phases.
__global__ __launch_bounds__(256) void gemm_proj(const __bf16* __restrict__ A,
                                                 const __bf16* __restrict__ Bt,
                                                 float* __restrict__ C,
                                                 int M, int N, int K) {
  __shared__ __bf16 As[2 * 64 * 32];
  __shared__ __bf16 Bs[2 * 128 * 32];
  int tid = threadIdx.x;
  int m0 = blockIdx.x * 64, n0 = blockIdx.y * 128;
  int w = tid >> 6, lane = tid & 63, quad = lane >> 4, l16 = lane & 15;
  int wm = (w >> 1) * 32, wn = (w & 1) * 64;

  f32x4 zero = {0.f, 0.f, 0.f, 0.f};
  f32x4 acc[2][4];
  for (int i = 0; i < 2; ++i) for (int j = 0; j < 4; ++j) acc[i][j] = zero;

  int rsub = lane >> 2, cc = (lane & 3) * 8;
  const __bf16* gA  = A  + (size_t)(m0 + w * 16 + rsub) * K + cc;
  const __bf16* gB0 = Bt + (size_t)(n0 + (2 * w) * 16 + rsub) * K + cc;
  const __bf16* gB1 = Bt + (size_t)(n0 + (2 * w + 1) * 16 + rsub) * K + cc;
  __bf16* lA0  = &As[w * 512];            __bf16* lA1  = &As[2048 + w * 512];
  __bf16* lB00 = &Bs[(2 * w) * 512];      __bf16* lB01 = &Bs[4096 + (2 * w) * 512];
  __bf16* lB10 = &Bs[(2 * w + 1) * 512];  __bf16* lB11 = &Bs[4096 + (2 * w + 1) * 512];

  for (int k0 = 0; k0 < K; k0 += 64) {
    __syncthreads();
    g2l16(gA + k0, lA0);       g2l16(gA + k0 + 32, lA1);
    g2l16(gB0 + k0, lB00);     g2l16(gB0 + k0 + 32, lB01);
    g2l16(gB1 + k0, lB10);     g2l16(gB1 + k0 + 32, lB11);
    __syncthreads();
    for (int ks = 0; ks < 2; ++ks) {
      bf16x8 af[2], bfr[4];
      for (int i = 0; i < 2; ++i)
        af[i] = *(const bf16x8*)(&As[ks * 2048 + (wm + i * 16 + l16) * 32 + quad * 8]);
      for (int j = 0; j < 4; ++j)
        bfr[j] = *(const bf16x8*)(&Bs[ks * 4096 + (wn + j * 16 + l16) * 32 + quad * 8]);
      for (int i = 0; i < 2; ++i)
        for (int j = 0; j < 4; ++j)
          acc[i][j] = __builtin_amdgcn_mfma_f32_16x16x32_bf16(af[i], bfr[j], acc[i][j], 0, 0, 0);
    }
  }
  for (int i = 0; i < 2; ++i)
    for (int j = 0; j < 4; ++j)
      for (int r = 0; r < 4; ++r)
        C[(size_t)(m0 + wm + i * 16 + quad * 4 + r) * N + n0 + wn + j * 16 + l16] = acc[i][j][r];
}

// ---------------- launch ----------------
extern "C" void kernel_launch(void* const* d_in, const int* in_sizes, int n_in,
                              void* d_out, int out_size, void* d_ws, size_t ws_size,
                              hipStream_t stream) {
  const float* x     = (const float*)d_in[0];
  const float* ve    = (const float*)d_in[1];
  const float* cosp  = (const float*)d_in[2];
  const float* sinp  = (const float*)d_in[3];
  const float* Wq    = (const float*)d_in[4];
  const float* Wk    = (const float*)d_in[5];
  const float* Wv    = (const float*)d_in[6];
  const float* Wproj = (const float*)d_in[7];
  const float* Wg    = (const float*)d_in[8];
  const int*   win   = (const int*)d_in[9];
  float* out = (float*)d_out;

  char* ws = (char*)d_ws;
  __bf16* xb   = (__bf16*)(ws);                //  8,388,608  [4096][1024]
  __bf16* Wt   = (__bf16*)(ws + 8388608);      //  3,145,728  [1536][1024]
  __bf16* Wpt  = (__bf16*)(ws + 11534336);     //  2,097,152  [1024][1024]
  float*  gate = (float*)(ws + 13631488);      //     65,536  [4096][4]
  __bf16* Qb   = (__bf16*)(ws + 13697024);     //  8,388,608  [2][16][2048][64]
  __bf16* Kb   = (__bf16*)(ws + 22085632);     //  2,097,152  [2][4][2048][64]
  __bf16* Vt   = (__bf16*)(ws + 24182784);     //  2,097,152  [2][4][64][2048]
  __bf16* Y    = (__bf16*)(ws + 26279936);     //  8,388,608  [4096][1024] -> ends 34,668,544

  prep<<<2048 + 4096, 256, 0, stream>>>(x, xb, gate, Wg, Wq, Wk, Wv, Wproj, Wt, Wpt);
  gemm_qkv<<<dim3(64, 12), 256, 0, stream>>>(xb, Wt, cosp, sinp, gate, ve, Qb, Kb, Vt);
  attn_kernel<<<dim3(16, 16, 2), 512, 0, stream>>>(Qb, Kb, Vt, Y, win);
  gemm_proj<<<dim3(64, 8), 256, 0, stream>>>(Y, Wpt, out, 4096, 1024, 1024);
}